// Round 12
// baseline (2364.732 us; speedup 1.0000x reference)
//
#include <hip/hip_runtime.h>
#include <hip/hip_bf16.h>
#include <stdint.h>

typedef unsigned short ushort_t;
typedef unsigned long long ull_t;
using bf16x8 = __attribute__((ext_vector_type(8))) short;
using f32x4  = __attribute__((ext_vector_type(4))) float;

#define SEQ    256
#define BATCH  64
#define INDIM  512
#define HDIM   1024
#define OUTDIM 256
#define MTOT   (SEQ*BATCH)   // 16384
#define BH     (BATCH*HDIM)
#define WPAD   1032          // padded row stride (ushorts) for LDS weights

__device__ __forceinline__ ushort_t f2bf(float f) {
  uint32_t u = __builtin_bit_cast(uint32_t, f);
  u += 0x7fffu + ((u >> 16) & 1u);
  return (ushort_t)(u >> 16);
}
__device__ __forceinline__ float bf2f(ushort_t b) {
  uint32_t u = ((uint32_t)b) << 16;
  return __builtin_bit_cast(float, u);
}
__device__ __forceinline__ f32x4 mfma16(bf16x8 a, bf16x8 b, f32x4 c) {
  return __builtin_amdgcn_mfma_f32_16x16x32_bf16(a, b, c, 0, 0, 0);
}
__device__ __forceinline__ void gload16(const void* g, void* l) {
  __builtin_amdgcn_global_load_lds(
      (const __attribute__((address_space(1))) unsigned int*)g,
      (__attribute__((address_space(3))) unsigned int*)l, 16, 0, 0);
}
__device__ __forceinline__ float tanhfast(float z) {
  float e = __expf(2.0f * z);
  return 1.0f - 2.0f / (e + 1.0f);
}
// L1-bypassing L2 read/store (flag fast path). waitcnt fused in asm (rule #18).
__device__ __forceinline__ int load_sc0_int(const int* p) {
  int v;
  asm volatile("global_load_dword %0, %1, off sc0\n\ts_waitcnt vmcnt(0)"
               : "=&v"(v) : "v"(p) : "memory");
  return v;
}
__device__ __forceinline__ void store_sc0_int(int* p, int v) {
  asm volatile("global_store_dword %0, %1, off sc0" :: "v"(p), "v"(v) : "memory");
}

// ---------------- prep kernels ----------------
__global__ void k_convert(const float* __restrict__ src, ushort_t* __restrict__ dst, int n) {
  int i = blockIdx.x * blockDim.x + threadIdx.x;
  if (i < n) dst[i] = f2bf(src[i]);
}
__global__ void k_split(const float* __restrict__ src, ushort_t* __restrict__ hi,
                        ushort_t* __restrict__ lo, int n) {
  int i = blockIdx.x * blockDim.x + threadIdx.x;
  if (i < n) {
    float v = src[i];
    ushort_t h = f2bf(v);
    hi[i] = h;
    lo[i] = f2bf(v - bf2f(h));
  }
}
__global__ void k_split_wc(const float* __restrict__ Wc,
                           ushort_t* __restrict__ WiH, ushort_t* __restrict__ WiL,
                           ushort_t* __restrict__ WhH, ushort_t* __restrict__ WhL) {
  int i = blockIdx.x * blockDim.x + threadIdx.x;
  if (i < HDIM * HDIM) {
    int row = i >> 10, k = i & 1023;
    float vi = Wc[(size_t)row * (2 * HDIM) + k];
    float vh = Wc[(size_t)row * (2 * HDIM) + HDIM + k];
    ushort_t ih = f2bf(vi);
    WiH[i] = ih; WiL[i] = f2bf(vi - bf2f(ih));
    ushort_t hh = f2bf(vh);
    WhH[i] = hh; WhL[i] = f2bf(vh - bf2f(hh));
  }
}

// ---------------- generic NT GEMM (validated r1-r11) ----------------
template<int SPLITB, int RELU, int OUTBF>
__global__ __launch_bounds__(256) void gemm_nt(
    const ushort_t* __restrict__ A, const ushort_t* __restrict__ Bhi,
    const ushort_t* __restrict__ Blo, const float* __restrict__ bias,
    float* __restrict__ Cf, ushort_t* __restrict__ Cb,
    int M, int N, int K)
{
  __shared__ ushort_t As[128 * 32];
  __shared__ ushort_t Bh[128 * 32];
  __shared__ ushort_t Bl[128 * 32];
  const int tid = threadIdx.x;
  const int w = tid >> 6, l = tid & 63;
  const int m0 = blockIdx.x * 128, n0 = blockIdx.y * 128;
  const int wr = w >> 1, wc = w & 1;
  const int lr = l & 15, lk = l >> 4;

  f32x4 acc[4][4] = {};
  const int nK = K >> 5;
  const size_t rowB = (size_t)K * 2;

  for (int kk = 0; kk < nK; ++kk) {
    const size_t kbyte = (size_t)kk * 64;
#pragma unroll
    for (int j = 0; j < 2; ++j) {
      int c = (w * 2 + j) * 64 + l;
      int row = c >> 2;
      int kb = (c & 3) * 16;
      gload16((const char*)A + (size_t)(m0 + row) * rowB + kbyte + kb,
              (char*)As + (w * 2 + j) * 1024);
      gload16((const char*)Bhi + (size_t)(n0 + row) * rowB + kbyte + kb,
              (char*)Bh + (w * 2 + j) * 1024);
      if (SPLITB)
        gload16((const char*)Blo + (size_t)(n0 + row) * rowB + kbyte + kb,
                (char*)Bl + (w * 2 + j) * 1024);
    }
    __syncthreads();
    bf16x8 af[4], bhf[4], blf[4];
#pragma unroll
    for (int i = 0; i < 4; ++i) {
      af[i]  = *(const bf16x8*)&As[(wr * 64 + i * 16 + lr) * 32 + lk * 8];
      bhf[i] = *(const bf16x8*)&Bh[(wc * 64 + i * 16 + lr) * 32 + lk * 8];
      if (SPLITB)
        blf[i] = *(const bf16x8*)&Bl[(wc * 64 + i * 16 + lr) * 32 + lk * 8];
    }
#pragma unroll
    for (int i = 0; i < 4; ++i)
#pragma unroll
      for (int j2 = 0; j2 < 4; ++j2) {
        acc[i][j2] = mfma16(af[i], bhf[j2], acc[i][j2]);
        if (SPLITB) acc[i][j2] = mfma16(af[i], blf[j2], acc[i][j2]);
      }
    __syncthreads();
  }
#pragma unroll
  for (int j2 = 0; j2 < 4; ++j2) {
    int n = n0 + wc * 64 + j2 * 16 + lr;
    float bv = bias ? bias[n] : 0.0f;
#pragma unroll
    for (int i = 0; i < 4; ++i) {
#pragma unroll
      for (int r = 0; r < 4; ++r) {
        int m = m0 + wr * 64 + i * 16 + lk * 4 + r;
        float v = acc[i][j2][r] + bv;
        if (RELU) v = fmaxf(v, 0.0f);
        if (OUTBF) Cb[(size_t)m * N + n] = f2bf(v);
        else       Cf[(size_t)m * N + n] = v;
      }
    }
  }
}

// ---------------- persistent scan kernel: poller-decoupled, zero-barrier -----
// 512 blocks x 576 threads (9 waves). Workers: XCDs 0-3 x 32 slots (claim via
// XCC_ID + atomic; over-provisioned grid -> hang-proof). Block (g,c): batch
// rows 16g..16g+15, cols 32c..32c+31.
// r12 (corrected r10): wave 8 = dedicated POLLER, free-running: polls 64
// per-tile A/B flags (dual path sc0+MALL), releases monotonic LDS epoch.
// Compute waves (8) = 4 tiles (phase x col-tile) x 2 K-halves: spin on LDS
// epoch only (no global poll storm - r10 fix #1), pairwise LDS seq reduce
// (flow-controlled by epoch; no block barrier in loop), 4 split accumulators
// (no serial MFMA chain - r10 fix #2), per-tile immediate flag publish after
// own vmcnt ack. Weights: WhH+WhL in LDS (132KB -> 1 block/CU); WiH in 64
// pinned VGPR (B-waves only). State archives SEQ-deep first-touch (r5).
// Iter i: A: h0(i)   = h0(i-1) + a0*tanh(P0[i] + Wh*h0(i-1))         [i<SEQ]
//         B: h1(i-1) = h1(i-2) + a1*tanh(WiH*h0(i-1)+Wh*h1(i-2)+b_c) [i>=1]
__global__ __launch_bounds__(576) void scan_kernel(
    const float* __restrict__ P0,
    const ushort_t* __restrict__ WiH, const ushort_t* __restrict__ WiL,
    const ushort_t* __restrict__ WhH, const ushort_t* __restrict__ WhL,
    const float* __restrict__ b_c, const float* __restrict__ taus,
    ushort_t* __restrict__ h0buf,   // SEQ x 64x1024 bf16 (archive)
    ushort_t* __restrict__ H1buf,   // SEQ x 64x1024 bf16 (archive = h1 state)
    float* __restrict__ outHidden, int* __restrict__ sync)
{
  __shared__ ushort_t WhHs[32 * WPAD];   // 66KB
  __shared__ ushort_t WhLs[32 * WPAD];   // 66KB
  __shared__ float slotf[4][64][4];      // pairwise partials, 4KB
  __shared__ int seqw[4 * 8];            // per-tile pairwise seq (stride 8)
  __shared__ int epoch[8];
  __shared__ int meta[2];

  const int tid = threadIdx.x;
  const int w = tid >> 6, l = tid & 63;
  const int lr = l & 15, lk = l >> 4;

  int* cnt    = sync;                    // [8] per-XCD slot counters
  int* A_l2   = sync + 256;              // [4*64] x 16-int spacing
  int* A_mall = sync + 256 + 4096;
  int* B_l2   = sync + 256 + 8192;
  int* B_mall = sync + 256 + 12288;

  // ---- placement discovery + LDS init ----
  if (tid == 0) {
    int xcd;
    asm volatile("s_getreg_b32 %0, hwreg(HW_REG_XCC_ID)" : "=s"(xcd));
    int slot = 999;
    if (xcd < 4)
      slot = __hip_atomic_fetch_add(&cnt[xcd], 1, __ATOMIC_RELAXED,
                                    __HIP_MEMORY_SCOPE_AGENT);
    meta[0] = (xcd < 4) ? xcd : -1;
    meta[1] = slot;
  }
  if (tid < 32) seqw[tid] = 0;
  if (tid < 8)  epoch[tid] = 0;
  __syncthreads();
  const int g = meta[0];
  const int c = meta[1];
  if (g < 0 || c >= 32) return;   // surplus block: exit, frees the CU

  const int rowg = g * 16, colg = c * 32;

  // ---- one-time: WhH + WhL slices -> LDS (reg-staged, padded rows) ----
  if (tid < 512) {
    const ushort_t* s1 = WhH + (size_t)colg * HDIM;
    const ushort_t* s2 = WhL + (size_t)colg * HDIM;
#pragma unroll
    for (int j = 0; j < 8; ++j) {
      int e = (j * 512 + tid) * 8;
      *(bf16x8*)&WhHs[(e >> 10) * WPAD + (e & 1023)] = *(const bf16x8*)&s1[e];
      *(bf16x8*)&WhLs[(e >> 10) * WPAD + (e & 1023)] = *(const bf16x8*)&s2[e];
    }
  }
  __syncthreads();   // one-time; the step loop has NO barriers

  // ================= POLLER WAVE =================
  if (w == 8) {
    const int* al2 = &A_l2[(g * 64 + l) * 16];
    int*       aml = &A_mall[(g * 64 + l) * 16];
    const int* bl2 = &B_l2[(g * 64 + l) * 16];
    int*       bml = &B_mall[(g * 64 + l) * 16];
    for (int i = 1; i <= SEQ; ++i) {
      const int tA = i, tB = i - 1;
      for (int r = 0;; ++r) {
        int va, vb;
        if ((r & 3) == 3) {
          va = __hip_atomic_load(aml, __ATOMIC_RELAXED, __HIP_MEMORY_SCOPE_AGENT);
          vb = __hip_atomic_load(bml, __ATOMIC_RELAXED, __HIP_MEMORY_SCOPE_AGENT);
        } else {
          asm volatile("global_load_dword %0, %2, off sc0\n\t"
                       "global_load_dword %1, %3, off sc0\n\t"
                       "s_waitcnt vmcnt(0)"
                       : "=&v"(va), "=&v"(vb) : "v"(al2), "v"(bl2) : "memory");
        }
        if (__all((va >= tA) && (vb >= tB))) break;
      }
      if (l == 0) *(volatile int*)&epoch[0] = i;
    }
    return;
  }

  // ================= COMPUTE WAVES =================
  const int pair = w & 3;          // tile: ph*2+ect
  const int ph = pair >> 1;        // 0 = layer0(A), 1 = layer1(B)
  const int ect = pair & 1;
  const int half = w >> 2;         // K-half
  const int tc = colg + ect * 16;
  const int ldsrow = (ect * 16 + lr) * WPAD + half * 512 + lk * 8;

  // B-waves: WiH K-half slice in regs (16 frags = 64 VGPR, pinned per-iter)
  bf16x8 wi[16];
  if (ph == 1) {
#pragma unroll
    for (int kk = 0; kk < 16; ++kk)
      wi[kk] = *(const bf16x8*)&WiH[(size_t)(tc + lr) * HDIM + half * 512 + kk * 32 + lk * 8];
  }

  // epilogue state (lo waves): lane = col tc+(l&15), rows rowg+(l>>4)*4..+3
  const int col = tc + (l & 15);
  const int row0 = rowg + (l >> 4) * 4;
  float hm[4] = {0, 0, 0, 0};
  float p0r[4] = {0, 0, 0, 0};
  const float alpha = 0.05f / (taus[ph] + 0.001f);
  const float bcn = b_c[col];
  int* myl2 = (ph == 0) ? &A_l2[(g * 64 + c * 2 + ect) * 16]
                        : &B_l2[(g * 64 + c * 2 + ect) * 16];
  int* myml = (ph == 0) ? &A_mall[(g * 64 + c * 2 + ect) * 16]
                        : &B_mall[(g * 64 + c * 2 + ect) * 16];
  if (half == 0 && ph == 0) {
#pragma unroll
    for (int j = 0; j < 4; ++j)
      p0r[j] = P0[((size_t)0 * BATCH + row0 + j) * HDIM + col];
  }

  for (int i = 0; i <= SEQ; ++i) {
    if (ph == 1) {
#pragma unroll
      for (int kk = 0; kk < 16; ++kk) asm volatile("" : "+v"(wi[kk]));
    }
    const bool act    = (ph == 0) ? (i < SEQ) : (i >= 1);
    const bool red_on = act && (i >= 1);

    if (i >= 1) {
      int t = 0;
      while (*(volatile int*)&epoch[0] < i) {
        if (++t > 8) { __builtin_amdgcn_s_sleep(1); t = 0; }
      }
      __builtin_amdgcn_sched_barrier(0);
      asm volatile("" ::: "memory");
    }

    f32x4 a0 = {}, a1 = {}, a2 = {}, a3 = {};
    if (red_on) {
      const ushort_t* h0p = h0buf + (size_t)(i - 1) * BH +
                            (size_t)(rowg + lr) * HDIM + half * 512 + lk * 8;
      if (ph == 0) {
#pragma unroll
        for (int kk = 0; kk < 16; ++kk) {
          bf16x8 f   = *(const bf16x8*)&h0p[kk * 32];
          bf16x8 whh = *(const bf16x8*)&WhHs[ldsrow + kk * 32];
          bf16x8 whl = *(const bf16x8*)&WhLs[ldsrow + kk * 32];
          if (kk & 1) { a0 = mfma16(f, whh, a0); a1 = mfma16(f, whl, a1); }
          else        { a2 = mfma16(f, whh, a2); a3 = mfma16(f, whl, a3); }
        }
      } else {
#pragma unroll
        for (int kk = 0; kk < 16; ++kk) {
          bf16x8 f = *(const bf16x8*)&h0p[kk * 32];
          if (kk & 1) a0 = mfma16(f, wi[kk], a0);
          else        a1 = mfma16(f, wi[kk], a1);
        }
        if (i >= 2) {
          const ushort_t* h1p = H1buf + (size_t)(i - 2) * BH +
                                (size_t)(rowg + lr) * HDIM + half * 512 + lk * 8;
#pragma unroll
          for (int kk = 0; kk < 16; ++kk) {
            bf16x8 hh  = *(const bf16x8*)&h1p[kk * 32];
            bf16x8 whh = *(const bf16x8*)&WhHs[ldsrow + kk * 32];
            bf16x8 whl = *(const bf16x8*)&WhLs[ldsrow + kk * 32];
            a2 = mfma16(hh, whh, a2);
            a3 = mfma16(hh, whl, a3);
          }
        }
      }
    }
    f32x4 acc = (a0 + a1) + (a2 + a3);

    if (half == 1) {
      if (red_on) {
        *(f32x4*)&slotf[pair][l] = acc;
        asm volatile("s_waitcnt lgkmcnt(0)" ::: "memory");
        if (l == 0) *(volatile int*)&seqw[pair * 8] = i + 1;
      }
    } else if (act) {
      if (red_on) {
        int t = 0;
        while (*(volatile int*)&seqw[pair * 8] < i + 1) {
          if (++t > 16) { __builtin_amdgcn_s_sleep(0); t = 0; }
        }
        __builtin_amdgcn_sched_barrier(0);
        asm volatile("" ::: "memory");
        acc += *(const f32x4*)&slotf[pair][l];
      }
      if (ph == 0) {
        ushort_t* dst = &h0buf[(size_t)i * BH + (size_t)row0 * HDIM + col];
#pragma unroll
        for (int j = 0; j < 4; ++j) {
          hm[j] += alpha * tanhfast(p0r[j] + acc[j]);
          dst[(size_t)j * HDIM] = f2bf(hm[j]);
        }
      } else {
        ushort_t* dst = &H1buf[(size_t)(i - 1) * BH + (size_t)row0 * HDIM + col];
#pragma unroll
        for (int j = 0; j < 4; ++j) {
          hm[j] += alpha * tanhfast(acc[j] + bcn);
          dst[(size_t)j * HDIM] = f2bf(hm[j]);
        }
      }
      asm volatile("s_waitcnt vmcnt(0)" ::: "memory");  // own stores acked at L2
      if (l == 0) {
        const int fv = (ph == 0) ? (i + 1) : i;
        store_sc0_int(myl2, fv);
        __hip_atomic_store(myml, fv, __ATOMIC_RELAXED, __HIP_MEMORY_SCOPE_AGENT);
      }
      if (ph == 0 && i + 1 < SEQ) {   // prefetch next P0 tile (off-chain)
#pragma unroll
        for (int j = 0; j < 4; ++j)
          p0r[j] = P0[((size_t)(i + 1) * BATCH + row0 + j) * HDIM + col];
      }
    }
  }

  // hidden_final [2][64][1024]
  if (half == 0) {
    float* dst = &outHidden[(size_t)ph * BH + (size_t)row0 * HDIM + col];
#pragma unroll
    for (int j = 0; j < 4; ++j) dst[(size_t)j * HDIM] = hm[j];
  }
}

// ---------------- host ----------------
extern "C" void kernel_launch(void* const* d_in, const int* in_sizes, int n_in,
                              void* d_out, int out_size, void* d_ws, size_t ws_size,
                              hipStream_t stream) {
  const float* x    = (const float*)d_in[0];
  const float* W_in = (const float*)d_in[1];
  const float* b_in = (const float*)d_in[2];
  const float* W_c  = (const float*)d_in[3];
  const float* b_c  = (const float*)d_in[4];
  const float* taus = (const float*)d_in[5];
  const float* W_o1 = (const float*)d_in[6];
  const float* b_o1 = (const float*)d_in[7];
  const float* W_o2 = (const float*)d_in[8];
  const float* b_o2 = (const float*)d_in[9];
  float* out = (float*)d_out;

  char* ws = (char*)d_ws;
  size_t off = 0;
  auto alloc = [&](size_t bytes) -> char* {
    char* p = ws + off;
    off += (bytes + 255) & ~(size_t)255;
    return p;
  };
  ushort_t* x_bf  = (ushort_t*)alloc((size_t)MTOT * INDIM * 2);     // 16 MB
  ushort_t* xp_b  = (ushort_t*)alloc((size_t)MTOT * HDIM * 2);      // 32 MB
  float*    P0    = (float*)   alloc((size_t)MTOT * HDIM * 4);      // 64 MB
  ushort_t* H1buf = (ushort_t*)alloc((size_t)MTOT * HDIM * 2);      // 32 MB
  ushort_t* h0buf = (ushort_t*)alloc((size_t)SEQ * BH * 2);         // 32 MB
  ushort_t* O1    = (ushort_t*)alloc((size_t)MTOT * (HDIM/2) * 2);  // 16 MB
  ushort_t* WiH   = (ushort_t*)alloc((size_t)HDIM * HDIM * 2);
  ushort_t* WiL   = (ushort_t*)alloc((size_t)HDIM * HDIM * 2);
  ushort_t* WhH   = (ushort_t*)alloc((size_t)HDIM * HDIM * 2);
  ushort_t* WhL   = (ushort_t*)alloc((size_t)HDIM * HDIM * 2);
  ushort_t* WinH  = (ushort_t*)alloc((size_t)HDIM * INDIM * 2);
  ushort_t* WinL  = (ushort_t*)alloc((size_t)HDIM * INDIM * 2);
  ushort_t* Wo1b  = (ushort_t*)alloc((size_t)(HDIM/2) * HDIM * 2);
  ushort_t* Wo2b  = (ushort_t*)alloc((size_t)OUTDIM * (HDIM/2) * 2);
  int*      sync  = (int*)     alloc(131072);
  if (off > ws_size) return;

  hipMemsetAsync(sync, 0, 131072, stream);

  k_convert<<<(MTOT * INDIM + 255) / 256, 256, 0, stream>>>(x, x_bf, MTOT * INDIM);
  k_split<<<(HDIM * INDIM + 255) / 256, 256, 0, stream>>>(W_in, WinH, WinL, HDIM * INDIM);
  k_split_wc<<<(HDIM * HDIM + 255) / 256, 256, 0, stream>>>(W_c, WiH, WiL, WhH, WhL);
  k_convert<<<((HDIM/2) * HDIM + 255) / 256, 256, 0, stream>>>(W_o1, Wo1b, (HDIM/2) * HDIM);
  k_convert<<<(OUTDIM * (HDIM/2) + 255) / 256, 256, 0, stream>>>(W_o2, Wo2b, OUTDIM * (HDIM/2));

  // xp = x @ W_in^T + b_in   -> bf16
  gemm_nt<1, 0, 1><<<dim3(MTOT / 128, HDIM / 128), 256, 0, stream>>>(
      x_bf, WinH, WinL, b_in, nullptr, xp_b, MTOT, HDIM, INDIM);
  // P0 = xp @ Wi^T + b_c     -> fp32
  gemm_nt<1, 0, 0><<<dim3(MTOT / 128, HDIM / 128), 256, 0, stream>>>(
      xp_b, WiH, WiL, b_c, P0, nullptr, MTOT, HDIM, HDIM);

  // sequential scan: 4 XCD-local groups x 32 worker blocks x 9 waves
  scan_kernel<<<512, 576, 0, stream>>>(P0, WiH, WiL, WhH, WhL, b_c, taus,
                                       h0buf, H1buf,
                                       out + (size_t)SEQ * BATCH * OUTDIM, sync);

  // O1 = relu(H1 @ W_o1^T + b_o1) -> bf16
  gemm_nt<0, 1, 1><<<dim3(MTOT / 128, (HDIM/2) / 128), 256, 0, stream>>>(
      H1buf, Wo1b, nullptr, b_o1, nullptr, O1, MTOT, HDIM / 2, HDIM);
  // out = O1 @ W_o2^T + b_o2 -> fp32
  gemm_nt<0, 0, 0><<<dim3(MTOT / 128, OUTDIM / 128), 256, 0, stream>>>(
      O1, Wo2b, nullptr, b_o2, out, nullptr, MTOT, OUTDIM, HDIM / 2);
}

// Round 13
// 1225.191 us; speedup vs baseline: 1.9301x; 1.9301x over previous
//
#include <hip/hip_runtime.h>
#include <hip/hip_bf16.h>
#include <stdint.h>

typedef unsigned short ushort_t;
typedef unsigned long long ull_t;
using bf16x8 = __attribute__((ext_vector_type(8))) short;
using f32x4  = __attribute__((ext_vector_type(4))) float;

#define SEQ    256
#define BATCH  64
#define INDIM  512
#define HDIM   1024
#define OUTDIM 256
#define MTOT   (SEQ*BATCH)   // 16384
#define BH     (BATCH*HDIM)

__device__ __forceinline__ ushort_t f2bf(float f) {
  uint32_t u = __builtin_bit_cast(uint32_t, f);
  u += 0x7fffu + ((u >> 16) & 1u);
  return (ushort_t)(u >> 16);
}
__device__ __forceinline__ float bf2f(ushort_t b) {
  uint32_t u = ((uint32_t)b) << 16;
  return __builtin_bit_cast(float, u);
}
__device__ __forceinline__ f32x4 mfma16(bf16x8 a, bf16x8 b, f32x4 c) {
  return __builtin_amdgcn_mfma_f32_16x16x32_bf16(a, b, c, 0, 0, 0);
}
__device__ __forceinline__ void gload16(const void* g, void* l) {
  __builtin_amdgcn_global_load_lds(
      (const __attribute__((address_space(1))) unsigned int*)g,
      (__attribute__((address_space(3))) unsigned int*)l, 16, 0, 0);
}
__device__ __forceinline__ float tanhfast(float z) {
  float e = __expf(2.0f * z);
  return 1.0f - 2.0f / (e + 1.0f);
}
// L1-bypassing L2 read (fast-path flag poll). waitcnt fused in asm (rule #18).
__device__ __forceinline__ int load_sc0_int(const int* p) {
  int v;
  asm volatile("global_load_dword %0, %1, off sc0\n\ts_waitcnt vmcnt(0)"
               : "=&v"(v) : "v"(p) : "memory");
  return v;
}

// ---------------- prep kernels ----------------
__global__ void k_convert(const float* __restrict__ src, ushort_t* __restrict__ dst, int n) {
  int i = blockIdx.x * blockDim.x + threadIdx.x;
  if (i < n) dst[i] = f2bf(src[i]);
}
__global__ void k_split(const float* __restrict__ src, ushort_t* __restrict__ hi,
                        ushort_t* __restrict__ lo, int n) {
  int i = blockIdx.x * blockDim.x + threadIdx.x;
  if (i < n) {
    float v = src[i];
    ushort_t h = f2bf(v);
    hi[i] = h;
    lo[i] = f2bf(v - bf2f(h));
  }
}
__global__ void k_split_wc(const float* __restrict__ Wc,
                           ushort_t* __restrict__ WiH, ushort_t* __restrict__ WiL,
                           ushort_t* __restrict__ WhH, ushort_t* __restrict__ WhL) {
  int i = blockIdx.x * blockDim.x + threadIdx.x;
  if (i < HDIM * HDIM) {
    int row = i >> 10, k = i & 1023;
    float vi = Wc[(size_t)row * (2 * HDIM) + k];
    float vh = Wc[(size_t)row * (2 * HDIM) + HDIM + k];
    ushort_t ih = f2bf(vi);
    WiH[i] = ih; WiL[i] = f2bf(vi - bf2f(ih));
    ushort_t hh = f2bf(vh);
    WhH[i] = hh; WhL[i] = f2bf(vh - bf2f(hh));
  }
}

// ---------------- generic NT GEMM (validated r1-r12) ----------------
template<int SPLITB, int RELU, int OUTBF>
__global__ __launch_bounds__(256) void gemm_nt(
    const ushort_t* __restrict__ A, const ushort_t* __restrict__ Bhi,
    const ushort_t* __restrict__ Blo, const float* __restrict__ bias,
    float* __restrict__ Cf, ushort_t* __restrict__ Cb,
    int M, int N, int K)
{
  __shared__ ushort_t As[128 * 32];
  __shared__ ushort_t Bh[128 * 32];
  __shared__ ushort_t Bl[128 * 32];
  const int tid = threadIdx.x;
  const int w = tid >> 6, l = tid & 63;
  const int m0 = blockIdx.x * 128, n0 = blockIdx.y * 128;
  const int wr = w >> 1, wc = w & 1;
  const int lr = l & 15, lk = l >> 4;

  f32x4 acc[4][4] = {};
  const int nK = K >> 5;
  const size_t rowB = (size_t)K * 2;

  for (int kk = 0; kk < nK; ++kk) {
    const size_t kbyte = (size_t)kk * 64;
#pragma unroll
    for (int j = 0; j < 2; ++j) {
      int c = (w * 2 + j) * 64 + l;
      int row = c >> 2;
      int kb = (c & 3) * 16;
      gload16((const char*)A + (size_t)(m0 + row) * rowB + kbyte + kb,
              (char*)As + (w * 2 + j) * 1024);
      gload16((const char*)Bhi + (size_t)(n0 + row) * rowB + kbyte + kb,
              (char*)Bh + (w * 2 + j) * 1024);
      if (SPLITB)
        gload16((const char*)Blo + (size_t)(n0 + row) * rowB + kbyte + kb,
                (char*)Bl + (w * 2 + j) * 1024);
    }
    __syncthreads();
    bf16x8 af[4], bhf[4], blf[4];
#pragma unroll
    for (int i = 0; i < 4; ++i) {
      af[i]  = *(const bf16x8*)&As[(wr * 64 + i * 16 + lr) * 32 + lk * 8];
      bhf[i] = *(const bf16x8*)&Bh[(wc * 64 + i * 16 + lr) * 32 + lk * 8];
      if (SPLITB)
        blf[i] = *(const bf16x8*)&Bl[(wc * 64 + i * 16 + lr) * 32 + lk * 8];
    }
#pragma unroll
    for (int i = 0; i < 4; ++i)
#pragma unroll
      for (int j2 = 0; j2 < 4; ++j2) {
        acc[i][j2] = mfma16(af[i], bhf[j2], acc[i][j2]);
        if (SPLITB) acc[i][j2] = mfma16(af[i], blf[j2], acc[i][j2]);
      }
    __syncthreads();
  }
#pragma unroll
  for (int j2 = 0; j2 < 4; ++j2) {
    int n = n0 + wc * 64 + j2 * 16 + lr;
    float bv = bias ? bias[n] : 0.0f;
#pragma unroll
    for (int i = 0; i < 4; ++i) {
#pragma unroll
      for (int r = 0; r < 4; ++r) {
        int m = m0 + wr * 64 + i * 16 + lk * 4 + r;
        float v = acc[i][j2][r] + bv;
        if (RELU) v = fmaxf(v, 0.0f);
        if (OUTBF) Cb[(size_t)m * N + n] = f2bf(v);
        else       Cf[(size_t)m * N + n] = v;
      }
    }
  }
}

// ---------------- persistent scan kernel: 16 waves (r7 champion) ------------
// 512 blocks x 1024 threads (16 waves). Workers: XCDs 0-3, 32 slots (claim via
// XCC_ID + atomic, over-provisioned grid -> hang-proof). K-slice 64/wave.
// State via XCD L2 (plain write-through stores + vmcnt ack; first-touch plain
// loads on SEQ-deep archives -> no stale L1). Flags dual-path (L2 sc0 + MALL
// fallback). Session conclusion (r5-r12): the scan is bound by the cross-CU
// handoff latency chain (~4.2us/step = max-over-32-producers of store->L2->
// flag->detect->load), not by data placement (r7 streams weights from L2 at
// the same speed as r8's LDS-resident variant) nor by protocol detail (8
// variants within 4.2-4.6us/step; both decoupling attempts regressed).
// Iter i: A: h0(i)   = h0(i-1) + a0*tanh(P0[i] + Wh*h0(i-1))         [i<SEQ]
//         B: h1(i-1) = h1(i-2) + a1*tanh(Wi*h0(i-1)+Wh*h1(i-2)+b_c)  [i>=1]
__global__ __launch_bounds__(1024, 4) void scan_kernel(
    const float* __restrict__ P0,
    const ushort_t* __restrict__ WiH, const ushort_t* __restrict__ WiL,
    const ushort_t* __restrict__ WhH, const ushort_t* __restrict__ WhL,
    const float* __restrict__ b_c, const float* __restrict__ taus,
    ushort_t* __restrict__ h0buf,   // SEQ x 64x1024 bf16 (archive)
    ushort_t* __restrict__ H1buf,   // SEQ x 64x1024 bf16 (archive = h1 state)
    float* __restrict__ outHidden, int* __restrict__ sync)
{
  __shared__ float red[4 * 16 * 320];   // [tile(ph,ct)][q=wave][col*20+row] = 80KB
  __shared__ int meta[2];

  const int tid = threadIdx.x;
  const int w = tid >> 6, l = tid & 63;
  const int lr = l & 15, lk = l >> 4;

  int* cnt        = sync;         // [8] per-XCD slot counters
  int* flags_l2   = sync + 64;    // [4][32] fast path (XCD L2)
  int* flags_mall = sync + 192;   // [4][32] fallback path (MALL)

  // ---- placement discovery ----
  if (tid == 0) {
    int xcd;
    asm volatile("s_getreg_b32 %0, hwreg(HW_REG_XCC_ID)" : "=s"(xcd));
    int slot = 999;
    if (xcd < 4)
      slot = __hip_atomic_fetch_add(&cnt[xcd], 1, __ATOMIC_RELAXED,
                                    __HIP_MEMORY_SCOPE_AGENT);
    meta[0] = (xcd < 4) ? xcd : -1;
    meta[1] = slot;
  }
  __syncthreads();
  const int g = meta[0];
  const int c = meta[1];
  if (g < 0 || c >= 32) return;   // surplus block: exit, frees the CU

  const int rowg = g * 16, colg = c * 32;
  const int kb = w * 64;          // K-slice 64 per wave

  // ---- one-time: weight slices (2 ct x 2 kk x 4 mats = 16 bf16x8 = 64 VGPR)
  bf16x8 whh[2][2], whl[2][2], wih[2][2], wil[2][2];
#pragma unroll
  for (int ct = 0; ct < 2; ++ct)
#pragma unroll
    for (int kk = 0; kk < 2; ++kk) {
      size_t off = (size_t)(colg + ct * 16 + lr) * HDIM + kb + kk * 32 + lk * 8;
      whh[ct][kk] = *(const bf16x8*)&WhH[off];
      whl[ct][kk] = *(const bf16x8*)&WhL[off];
      wih[ct][kk] = *(const bf16x8*)&WiH[off];
      wil[ct][kk] = *(const bf16x8*)&WiL[off];
    }

  // epilogue mapping (waves 0-3): tile = w = ph*2+ct; lane owns col ec, rows R0..R0+3
  const int ep = (w < 4);
  const int ph = w >> 1, ect = w & 1;
  const int ec = lr, R0 = lk * 4;
  float hm[4] = {0, 0, 0, 0};
  float bcn = 0.f, alpha = 0.f;
  float p0r[4] = {0, 0, 0, 0};
  if (ep) {
    alpha = 0.05f / (taus[ph] + 0.001f);
    bcn = b_c[colg + ect * 16 + ec];
    if (ph == 0) {
#pragma unroll
      for (int j = 0; j < 4; ++j)
        p0r[j] = P0[((size_t)0 * BATCH + rowg + R0 + j) * HDIM + colg + ect * 16 + ec];
    }
  }

  for (int i = 0; i <= SEQ; ++i) {
    // pin weights live across the backedge (defeat remat/spill of the slice)
#pragma unroll
    for (int ct = 0; ct < 2; ++ct)
#pragma unroll
      for (int kk = 0; kk < 2; ++kk)
        asm volatile("" : "+v"(whh[ct][kk]), "+v"(whl[ct][kk]),
                          "+v"(wih[ct][kk]), "+v"(wil[ct][kk]));

    bf16x8 f0 = {}, f1 = {}, g0 = {}, g1 = {};
    f32x4 aA[2] = {}, aI[2] = {}, aH[2] = {};
    if (i >= 1) {
      const ushort_t* h0r = h0buf + (size_t)(i - 1) * BH;   // first touch
      f0 = *(const bf16x8*)&h0r[(size_t)(rowg + lr) * HDIM + kb + lk * 8];
      f1 = *(const bf16x8*)&h0r[(size_t)(rowg + lr) * HDIM + kb + 32 + lk * 8];
      if (i >= 2) {
        const ushort_t* h1r = H1buf + (size_t)(i - 2) * BH; // first touch
        g0 = *(const bf16x8*)&h1r[(size_t)(rowg + lr) * HDIM + kb + lk * 8];
        g1 = *(const bf16x8*)&h1r[(size_t)(rowg + lr) * HDIM + kb + 32 + lk * 8];
      }
#pragma unroll
      for (int ct = 0; ct < 2; ++ct) {
        aA[ct] = mfma16(f0, whh[ct][0], aA[ct]);
        aA[ct] = mfma16(f0, whl[ct][0], aA[ct]);
        aA[ct] = mfma16(f1, whh[ct][1], aA[ct]);
        aA[ct] = mfma16(f1, whl[ct][1], aA[ct]);
        aI[ct] = mfma16(f0, wih[ct][0], aI[ct]);
        aI[ct] = mfma16(f0, wil[ct][0], aI[ct]);
        aI[ct] = mfma16(f1, wih[ct][1], aI[ct]);
        aI[ct] = mfma16(f1, wil[ct][1], aI[ct]);
      }
      if (i >= 2) {
#pragma unroll
        for (int ct = 0; ct < 2; ++ct) {
          aH[ct] = mfma16(g0, whh[ct][0], aH[ct]);
          aH[ct] = mfma16(g0, whl[ct][0], aH[ct]);
          aH[ct] = mfma16(g1, whh[ct][1], aH[ct]);
          aH[ct] = mfma16(g1, whl[ct][1], aH[ct]);
        }
      }
    }
    // write partials: D-layout col=l&15, row=lk*4+r -> red[col*20+row] (b128)
    const int wbase = lr * 20 + lk * 4;
#pragma unroll
    for (int ct = 0; ct < 2; ++ct) {
      *(f32x4*)&red[((0 + ct) * 16 + w) * 320 + wbase] = aA[ct];
      f32x4 pb = aI[ct] + aH[ct];
      *(f32x4*)&red[((2 + ct) * 16 + w) * 320 + wbase] = pb;
    }
    __syncthreads();                                   // B1

    if (ep && ((ph == 0 && i < SEQ) || (ph == 1 && i >= 1))) {
      f32x4 s = {};
      const float* rb = &red[(w * 16) * 320 + ec * 20 + R0];
#pragma unroll
      for (int q = 0; q < 16; ++q)
        s += *(const f32x4*)&rb[q * 320];
      if (ph == 0) {
        ushort_t* dst = &h0buf[(size_t)i * BH + (size_t)(rowg + R0) * HDIM +
                               colg + ect * 16 + ec];
#pragma unroll
        for (int j = 0; j < 4; ++j) {
          hm[j] += alpha * tanhfast(p0r[j] + s[j]);
          dst[(size_t)j * HDIM] = f2bf(hm[j]);
        }
      } else {
        ushort_t* dst = &H1buf[(size_t)(i - 1) * BH + (size_t)(rowg + R0) * HDIM +
                               colg + ect * 16 + ec];
#pragma unroll
        for (int j = 0; j < 4; ++j) {
          hm[j] += alpha * tanhfast(s[j] + bcn);
          dst[(size_t)j * HDIM] = f2bf(hm[j]);
        }
      }
      asm volatile("s_waitcnt vmcnt(0)" ::: "memory"); // stores acked at L2
    }
    __syncthreads();                                   // B2

    if (i < SEQ) {
      if (tid == 0) {
        *(volatile int*)&flags_l2[g * 32 + c] = i + 1;   // write-through -> L2
        asm volatile("" ::: "memory");
        __hip_atomic_store(&flags_mall[g * 32 + c], i + 1, __ATOMIC_RELAXED,
                           __HIP_MEMORY_SCOPE_AGENT);    // MALL fallback
      }
      if (ep && ph == 0 && i + 1 < SEQ) {
#pragma unroll
        for (int j = 0; j < 4; ++j)
          p0r[j] = P0[((size_t)(i + 1) * BATCH + rowg + R0 + j) * HDIM +
                      colg + ect * 16 + ec];
      }
      if (w == 4) {
        const int target = i + 1;
        const int* fl2 = &flags_l2[g * 32 + (l & 31)];
        int* fml = &flags_mall[g * 32 + (l & 31)];
        for (int r = 0;; ++r) {
          int v = ((r & 3) == 3)
            ? __hip_atomic_load(fml, __ATOMIC_RELAXED, __HIP_MEMORY_SCOPE_AGENT)
            : load_sc0_int(fl2);
          if (__all(v >= target)) break;
        }
      }
      __syncthreads();                                 // B3
    }
  }

  // hidden_final [2][64][1024]: layer = ph
  if (ep) {
    float* dst = &outHidden[(size_t)ph * BH + (size_t)(rowg + R0) * HDIM +
                            colg + ect * 16 + ec];
#pragma unroll
    for (int j = 0; j < 4; ++j) dst[(size_t)j * HDIM] = hm[j];
  }
}

// ---------------- host ----------------
extern "C" void kernel_launch(void* const* d_in, const int* in_sizes, int n_in,
                              void* d_out, int out_size, void* d_ws, size_t ws_size,
                              hipStream_t stream) {
  const float* x    = (const float*)d_in[0];
  const float* W_in = (const float*)d_in[1];
  const float* b_in = (const float*)d_in[2];
  const float* W_c  = (const float*)d_in[3];
  const float* b_c  = (const float*)d_in[4];
  const float* taus = (const float*)d_in[5];
  const float* W_o1 = (const float*)d_in[6];
  const float* b_o1 = (const float*)d_in[7];
  const float* W_o2 = (const float*)d_in[8];
  const float* b_o2 = (const float*)d_in[9];
  float* out = (float*)d_out;

  char* ws = (char*)d_ws;
  size_t off = 0;
  auto alloc = [&](size_t bytes) -> char* {
    char* p = ws + off;
    off += (bytes + 255) & ~(size_t)255;
    return p;
  };
  ushort_t* x_bf  = (ushort_t*)alloc((size_t)MTOT * INDIM * 2);     // 16 MB
  ushort_t* xp_b  = (ushort_t*)alloc((size_t)MTOT * HDIM * 2);      // 32 MB
  float*    P0    = (float*)   alloc((size_t)MTOT * HDIM * 4);      // 64 MB
  ushort_t* H1buf = (ushort_t*)alloc((size_t)MTOT * HDIM * 2);      // 32 MB
  ushort_t* h0buf = (ushort_t*)alloc((size_t)SEQ * BH * 2);         // 32 MB
  ushort_t* O1    = (ushort_t*)alloc((size_t)MTOT * (HDIM/2) * 2);  // 16 MB
  ushort_t* WiH   = (ushort_t*)alloc((size_t)HDIM * HDIM * 2);
  ushort_t* WiL   = (ushort_t*)alloc((size_t)HDIM * HDIM * 2);
  ushort_t* WhH   = (ushort_t*)alloc((size_t)HDIM * HDIM * 2);
  ushort_t* WhL   = (ushort_t*)alloc((size_t)HDIM * HDIM * 2);
  ushort_t* WinH  = (ushort_t*)alloc((size_t)HDIM * INDIM * 2);
  ushort_t* WinL  = (ushort_t*)alloc((size_t)HDIM * INDIM * 2);
  ushort_t* Wo1b  = (ushort_t*)alloc((size_t)(HDIM/2) * HDIM * 2);
  ushort_t* Wo2b  = (ushort_t*)alloc((size_t)OUTDIM * (HDIM/2) * 2);
  int*      sync  = (int*)     alloc(4096);
  if (off > ws_size) return;

  hipMemsetAsync(sync, 0, 4096, stream);

  k_convert<<<(MTOT * INDIM + 255) / 256, 256, 0, stream>>>(x, x_bf, MTOT * INDIM);
  k_split<<<(HDIM * INDIM + 255) / 256, 256, 0, stream>>>(W_in, WinH, WinL, HDIM * INDIM);
  k_split_wc<<<(HDIM * HDIM + 255) / 256, 256, 0, stream>>>(W_c, WiH, WiL, WhH, WhL);
  k_convert<<<((HDIM/2) * HDIM + 255) / 256, 256, 0, stream>>>(W_o1, Wo1b, (HDIM/2) * HDIM);
  k_convert<<<(OUTDIM * (HDIM/2) + 255) / 256, 256, 0, stream>>>(W_o2, Wo2b, OUTDIM * (HDIM/2));

  // xp = x @ W_in^T + b_in   -> bf16
  gemm_nt<1, 0, 1><<<dim3(MTOT / 128, HDIM / 128), 256, 0, stream>>>(
      x_bf, WinH, WinL, b_in, nullptr, xp_b, MTOT, HDIM, INDIM);
  // P0 = xp @ Wi^T + b_c     -> fp32
  gemm_nt<1, 0, 0><<<dim3(MTOT / 128, HDIM / 128), 256, 0, stream>>>(
      xp_b, WiH, WiL, b_c, P0, nullptr, MTOT, HDIM, HDIM);

  // sequential scan: 4 XCD-local groups x 32 worker blocks x 16 waves
  scan_kernel<<<512, 1024, 0, stream>>>(P0, WiH, WiL, WhH, WhL, b_c, taus,
                                        h0buf, H1buf,
                                        out + (size_t)SEQ * BATCH * OUTDIM, sync);

  // O1 = relu(H1 @ W_o1^T + b_o1) -> bf16
  gemm_nt<0, 1, 1><<<dim3(MTOT / 128, (HDIM/2) / 128), 256, 0, stream>>>(
      H1buf, Wo1b, nullptr, b_o1, nullptr, O1, MTOT, HDIM / 2, HDIM);
  // out = O1 @ W_o2^T + b_o2 -> fp32
  gemm_nt<0, 0, 0><<<dim3(MTOT / 128, OUTDIM / 128), 256, 0, stream>>>(
      O1, Wo2b, nullptr, b_o2, out, nullptr, MTOT, OUTDIM, HDIM / 2);
}